// Round 11
// baseline (171.221 us; speedup 1.0000x reference)
//
#include <hip/hip_runtime.h>
#include <stdint.h>

typedef __bf16 bf16x8 __attribute__((ext_vector_type(8)));
typedef float f32x4 __attribute__((ext_vector_type(4)));
typedef unsigned short ushort8v __attribute__((ext_vector_type(8)));

static constexpr int SUBSETS = 3;
static constexpr int M = 4096;
static constexpr int D = 128;
static constexpr int NROWS = SUBSETS * M;    // 12288
static constexpr int NTGT = 512;             // targets per subset
static constexpr int NBKT = SUBSETS * NTGT;  // 1536

// ---- pass1 geometry (R5's proven structure) ----
static constexpr int WG_ROWS = 128;          // 4 waves x 32 rows
static constexpr int WG_COLS = 256;          // shared column strip per WG
static constexpr int NSTRIP = M / WG_COLS;   // 16
static constexpr int NRBWG = M / WG_ROWS;    // 32
static constexpr int WGS1 = SUBSETS * NRBWG * NSTRIP;  // 1536
static constexpr int SCOLS = 32;             // cols per LDS stage (8 KB)
static constexpr int NSTAGE = WG_COLS / SCOLS;         // 8

static constexpr int NSLOTS = 64;            // neg sims > 0.45 per row (~9 total GPU-wide)
#define NEG_KEEP 0.45f                        // < thrN_min(0.5); exact-capture margin

#define MARGIN_F 0.1f
#define NEGINF (-1e30f)

// ---------------- kernel 0: f32 -> bf16 (RNE) + zero scalar & counters ----
__global__ void cvt_f32_bf16(const float* __restrict__ in,
                             unsigned short* __restrict__ out, int n8,
                             float* __restrict__ loss_out,
                             unsigned int* __restrict__ ncnt) {
    int i = blockIdx.x * blockDim.x + threadIdx.x;
    if (i == 0) *loss_out = 0.0f;
    if (i < NROWS) ncnt[i] = 0u;
    if (i >= n8) return;
    const float4* p = reinterpret_cast<const float4*>(in) + (size_t)i * 2;
    float4 a = p[0];
    float4 b = p[1];
    float v[8] = {a.x, a.y, a.z, a.w, b.x, b.y, b.z, b.w};
    ushort8v r;
#pragma unroll
    for (int j = 0; j < 8; ++j) {
        uint32_t u = __builtin_bit_cast(uint32_t, v[j]);
        u = (u + 0x7FFFu + ((u >> 16) & 1u)) >> 16;  // RNE to bf16
        r[j] = (unsigned short)u;
    }
    *(reinterpret_cast<ushort8v*>(out) + i) = r;
}

// ---------------- kernel 1: bucket rows by (subset, target) ----------------
// One WG of 1024 threads: LDS histogram -> Hillis-Steele scan -> scatter.
__global__ __launch_bounds__(1024) void buckets(
        const int* __restrict__ tgt,
        unsigned int* __restrict__ bcnt,
        unsigned int* __restrict__ bstart,
        unsigned int* __restrict__ rowlist) {
    __shared__ unsigned int hist[NBKT];
    __shared__ unsigned int pref[2048];
    __shared__ unsigned int cur[NBKT];
    const int tid = threadIdx.x;
    for (int i = tid; i < NBKT; i += 1024) hist[i] = 0u;
    __syncthreads();
    for (int r = tid; r < NROWS; r += 1024) {
        const int b = (r >> 12) * NTGT + tgt[r];
        atomicAdd(&hist[b], 1u);
    }
    __syncthreads();
    for (int i = tid; i < 2048; i += 1024) pref[i] = (i < NBKT) ? hist[i] : 0u;
    __syncthreads();
    for (int off = 1; off < 2048; off <<= 1) {
        unsigned int v0 = 0, v1 = 0;
        const int i0 = tid, i1 = tid + 1024;
        if (i0 >= off) v0 = pref[i0 - off];
        if (i1 >= off) v1 = pref[i1 - off];
        __syncthreads();
        pref[i0] += v0;
        pref[i1] += v1;
        __syncthreads();
    }
    for (int i = tid; i < NBKT; i += 1024) {
        const unsigned int st = i ? pref[i - 1] : 0u;
        bstart[i] = st;
        bcnt[i] = hist[i];
        cur[i] = st;
    }
    __syncthreads();
    for (int r = tid; r < NROWS; r += 1024) {
        const int b = (r >> 12) * NTGT + tgt[r];
        const unsigned int pos = atomicAdd(&cur[b], 1u);
        rowlist[pos] = (unsigned int)r;
    }
}

// Stage SCOLS=32 cols (8 KB) of B into LDS, coalesced, inverse-swizzled source
// so the swizzled ds_read is conflict-free (rule #21).
__device__ __forceinline__ void stage_tile(const unsigned short* __restrict__ base,
                                           unsigned short* __restrict__ ldsbuf,
                                           int w, int lane) {
#pragma unroll
    for (int i = 0; i < 2; ++i) {
        const int slocal = w * 2048 + i * 1024 + lane * 16;
        const int col = slocal >> 8;
        const int off = (slocal & 255) ^ ((col & 7) << 4);
        const char* gsrc = (const char*)base + col * 256 + off;
        char* ldst = (char*)ldsbuf + w * 2048 + i * 1024;
        __builtin_amdgcn_global_load_lds(
            (const __attribute__((address_space(1))) void*)gsrc,
            (__attribute__((address_space(3))) void*)ldst,
            16, 0, 0);
    }
}

__device__ __forceinline__ bf16x8 lds_bfrag(const unsigned short* __restrict__ ldsbuf,
                                            int tt, int llo, int lhi, int kb) {
    const int col = tt * 16 + llo;
    const int off = (kb * 64 + lhi * 16) ^ ((col & 7) << 4);
    return *reinterpret_cast<const bf16x8*>((const char*)ldsbuf + col * 256 + off);
}

// ---------------- kernel 2: single GEMM pass — max_neg + rare neg appends ----
__global__ __launch_bounds__(256) void pass1(
        const unsigned short* __restrict__ ebf,
        const int* __restrict__ tgt,
        float* __restrict__ wsmax,        // [SUBSETS][M][NSTRIP] max_neg partials
        unsigned int* __restrict__ ncnt,  // [NROWS]
        float* __restrict__ pneg) {       // [NROWS][NSLOTS]
    __shared__ unsigned short lds[2][SCOLS * D];  // 2 x 8 KB

    const int wg = blockIdx.x;
    const int s = wg >> 9;
    const int rem = wg & 511;
    const int rbWG = rem & 31;
    const int cs = rem >> 5;

    const int tid = threadIdx.x;
    const int w = tid >> 6, lane = tid & 63;
    const int lhi = lane >> 4, llo = lane & 15;

    const unsigned short* E = ebf + (size_t)s * M * D;
    const int* T = tgt + s * M;
    const int rowBase = rbWG * WG_ROWS + w * 32;
    const int colBase = cs * WG_COLS;

    stage_tile(E + (size_t)colBase * D, lds[0], w, lane);

    bf16x8 a[2][4];
#pragma unroll
    for (int rr = 0; rr < 2; ++rr) {
        const int row = rowBase + rr * 16 + llo;
#pragma unroll
        for (int kb = 0; kb < 4; ++kb)
            a[rr][kb] = *reinterpret_cast<const bf16x8*>(
                E + (size_t)row * D + kb * 32 + lhi * 8);
    }
    int trow[2][4];
#pragma unroll
    for (int rr = 0; rr < 2; ++rr)
#pragma unroll
        for (int r = 0; r < 4; ++r)
            trow[rr][r] = T[rowBase + rr * 16 + lhi * 4 + r];

    float mn[2][4];
#pragma unroll
    for (int rr = 0; rr < 2; ++rr)
#pragma unroll
        for (int r = 0; r < 4; ++r) mn[rr][r] = NEGINF;

    __syncthreads();

    for (int st = 0; st < NSTAGE; ++st) {
        const int buf = st & 1;
        if (st + 1 < NSTAGE)
            stage_tile(E + (size_t)(colBase + (st + 1) * SCOLS) * D, lds[buf ^ 1], w, lane);
#pragma unroll
        for (int tt = 0; tt < 2; ++tt) {
            const int bcol = colBase + st * SCOLS + tt * 16 + llo;
            bf16x8 b[4];
#pragma unroll
            for (int kb = 0; kb < 4; ++kb) b[kb] = lds_bfrag(lds[buf], tt, llo, lhi, kb);
            const int tcol = T[bcol];
#pragma unroll
            for (int rr = 0; rr < 2; ++rr) {
                f32x4 acc = {0.f, 0.f, 0.f, 0.f};
#pragma unroll
                for (int kb = 0; kb < 4; ++kb)
                    acc = __builtin_amdgcn_mfma_f32_16x16x32_bf16(a[rr][kb], b[kb], acc, 0, 0, 0);
#pragma unroll
                for (int r = 0; r < 4; ++r) {
                    const float sv = acc[r];
                    const bool same = (tcol == trow[rr][r]);
                    // masked max over negatives (diagonal is same-target -> excluded)
                    mn[rr][r] = fmaxf(mn[rr][r], same ? NEGINF : sv);
                    // ultra-rare candidate capture (thrN >= 0.5 always; keep > 0.45)
                    if (!same && sv > NEG_KEEP) {
                        const int gRow = s * M + rowBase + rr * 16 + lhi * 4 + r;
                        const unsigned int idx = atomicAdd(&ncnt[gRow], 1u);
                        if (idx < NSLOTS) pneg[(size_t)gRow * NSLOTS + idx] = sv;
                    }
                }
            }
        }
        __syncthreads();
    }

#pragma unroll
    for (int rr = 0; rr < 2; ++rr)
#pragma unroll
        for (int r = 0; r < 4; ++r) {
#pragma unroll
            for (int off = 1; off < 16; off <<= 1)
                mn[rr][r] = fmaxf(mn[rr][r], __shfl_xor(mn[rr][r], off));
        }
    if (llo == 0) {
#pragma unroll
        for (int rr = 0; rr < 2; ++rr)
#pragma unroll
            for (int r = 0; r < 4; ++r) {
                const int row = rowBase + rr * 16 + lhi * 4 + r;
                wsmax[((size_t)s * M + row) * NSTRIP + cs] = mn[rr][r];
            }
    }
}

// ---------------- kernel 3: fixup — positives from buckets + thresholds ----
// One wave per (subset,target) bucket. Lane owns a row; partner loop is
// wave-uniform (broadcast reads, L1-hot: bucket working set ~2-8 KB).
__global__ __launch_bounds__(256) void fixup(
        const unsigned short* __restrict__ ebf,
        const unsigned int* __restrict__ bcnt,
        const unsigned int* __restrict__ bstart,
        const unsigned int* __restrict__ rowlist,
        const float* __restrict__ wsmax,
        const unsigned int* __restrict__ ncnt,
        const float* __restrict__ pneg,
        float* __restrict__ out) {
    const int b = blockIdx.x * 4 + (threadIdx.x >> 6);
    const int lane = threadIdx.x & 63;
    float tot = 0.f;
    const unsigned int c = bcnt[b];
    if (c >= 2) {
        const unsigned int start = bstart[b];
        for (unsigned int ibase = 0; ibase < c; ibase += 64) {
            const unsigned int mi = ibase + (unsigned int)lane;
            const bool valid = (mi < c);
            const unsigned int grow = rowlist[start + (valid ? mi : 0u)];
            // own row: 128 bf16 = 64 u32 in registers (static indices only)
            unsigned int own[64];
            const unsigned int* op =
                reinterpret_cast<const unsigned int*>(ebf + (size_t)grow * D);
#pragma unroll
            for (int k = 0; k < 64; ++k) own[k] = op[k];
            // thrP from strip maxes (16 f32 = 4x float4)
            const int s = grow >> 12, row = grow & (M - 1);
            const float4* wp = reinterpret_cast<const float4*>(
                &wsmax[((size_t)s * M + row) * NSTRIP]);
            float mneg = NEGINF;
#pragma unroll
            for (int k = 0; k < 4; ++k) {
                float4 v = wp[k];
                mneg = fmaxf(mneg, fmaxf(fmaxf(v.x, v.y), fmaxf(v.z, v.w)));
            }
            const float thrP = mneg + MARGIN_F;

            float mpos = NEGINF, ploss = 0.f;
            for (unsigned int j = 0; j < c; ++j) {
                const unsigned int prow = rowlist[start + j];  // wave-uniform
                const unsigned int* pp =
                    reinterpret_cast<const unsigned int*>(ebf + (size_t)prow * D);
                float acc = 0.f;
#pragma unroll 8
                for (int k = 0; k < 64; ++k) {
                    const unsigned int pv = pp[k], ov = own[k];
                    const float p0 = __builtin_bit_cast(float, pv << 16);
                    const float p1 = __builtin_bit_cast(float, pv & 0xffff0000u);
                    const float o0 = __builtin_bit_cast(float, ov << 16);
                    const float o1 = __builtin_bit_cast(float, ov & 0xffff0000u);
                    acc = fmaf(o0, p0, acc);
                    acc = fmaf(o1, p1, acc);
                }
                if (valid && j != mi) {
                    mpos = fmaxf(mpos, acc);
                    ploss += (acc < thrP) ? (1.0f - acc) : 0.0f;
                }
            }
            if (valid && mpos > -1e29f) {   // has_pos (c>=2 guarantees, but exact)
                const float thrN = fmaxf(0.6f, mpos) - MARGIN_F;
                float nloss = 0.f;
                const unsigned int nc = min(ncnt[grow], (unsigned int)NSLOTS);
                for (unsigned int i2 = 0; i2 < nc; ++i2) {
                    const float v = pneg[(size_t)grow * NSLOTS + i2];
                    nloss += (v > thrN) ? v : 0.0f;
                }
                tot += ploss + nloss;
            }
        }
    }
#pragma unroll
    for (int off = 1; off < 64; off <<= 1) tot += __shfl_xor(tot, off);
    if (lane == 0) atomicAdd(out, tot * (1.0f / 12288.0f));
}

extern "C" void kernel_launch(void* const* d_in, const int* in_sizes, int n_in,
                              void* d_out, int out_size, void* d_ws, size_t ws_size,
                              hipStream_t stream) {
    const float* emb = (const float*)d_in[0];
    const int* tgt = (const int*)d_in[1];
    float* out = (float*)d_out;

    char* ws = (char*)d_ws;
    unsigned short* ebf = (unsigned short*)ws;                        // 3 MB
    float* wsmax = (float*)(ws + (4u << 20));                         // 786 KB
    unsigned int* ncnt = (unsigned int*)(ws + (5u << 20));            // 48 KB
    float* pneg = (float*)(ws + (5u << 20) + (1u << 19));             // 3 MB
    unsigned int* bcnt = (unsigned int*)(ws + (9u << 20));            // 6 KB
    unsigned int* bstart = (unsigned int*)(ws + (9u << 20) + 16384);  // 6 KB
    unsigned int* rowlist = (unsigned int*)(ws + (9u << 20) + 32768); // 48 KB

    const int n = SUBSETS * M * D;
    const int n8 = n / 8;

    cvt_f32_bf16<<<n8 / 256, 256, 0, stream>>>(emb, ebf, n8, out, ncnt);
    buckets<<<1, 1024, 0, stream>>>(tgt, bcnt, bstart, rowlist);
    pass1<<<WGS1, 256, 0, stream>>>(ebf, tgt, wsmax, ncnt, pneg);
    fixup<<<NBKT / 4, 256, 0, stream>>>(ebf, bcnt, bstart, rowlist,
                                        wsmax, ncnt, pneg, out);
}